// Round 2
// baseline (1690.473 us; speedup 1.0000x reference)
//
#include <hip/hip_runtime.h>

#define BB 512
#define V0 1024
#define V1 256
#define V2 64
#define E0 8192
#define E1 2048

// ---------------- CSR build (deterministic) ----------------
__global__ void k_deg(const int* __restrict__ rows, int E, int* __restrict__ deg) {
    int t = blockIdx.x * 256 + threadIdx.x;
    if (t < E) atomicAdd(&deg[rows[t]], 1);
}

__global__ void k_scan(const int* __restrict__ deg, int* __restrict__ off, int V) {
    __shared__ int s[1024];
    int t = threadIdx.x;
    s[t] = (t < V) ? deg[t] : 0;
    __syncthreads();
    for (int d = 1; d < 1024; d <<= 1) {
        int val = (t >= d) ? s[t - d] : 0;
        __syncthreads();
        s[t] += val;
        __syncthreads();
    }
    if (t < V) off[t + 1] = s[t];
    if (t == 0) off[0] = 0;
}

// stable fill: edge e goes to off[row] + (#earlier edges with same row)
__global__ void k_fill(const int* __restrict__ rows, const int* __restrict__ cols,
                       const float* __restrict__ vals, int E,
                       const int* __restrict__ off, int* __restrict__ scol,
                       float* __restrict__ sval) {
    __shared__ int rs[256];
    int e = blockIdx.x * 256 + threadIdx.x;
    int r = (e < E) ? rows[e] : -1;
    int rank = 0;
    for (int c0 = 0; c0 <= (int)blockIdx.x; ++c0) {
        __syncthreads();
        int idx = c0 * 256 + threadIdx.x;
        rs[threadIdx.x] = (idx < E) ? rows[idx] : -2;
        __syncthreads();
        int lim = e - c0 * 256;
        if (lim > 256) lim = 256;
        for (int j = 0; j < lim; ++j) rank += (rs[j] == r) ? 1 : 0;
    }
    if (e < E) {
        int p = off[r] + rank;
        scol[p] = cols[e];
        sval[p] = vals[e];
    }
}

// ---------------- fused cheby conv, batch-major, per-b LDS staging ----------------
// Layouts: xin [B, V, FIN], out [B, V(or V/4), FOUT]. One block per batch element.
// Per feature-slice phase: stage x0 slice in LDS, compute x1 = L x0 in LDS,
// then per owned vertex: g = L x1 (LDS gather), accumulate
//   acc[o] += x0 * (W0 - W2) + x1 * W1 + g * (2 * W2)
// POOLMODE: 0 = none, 1 = register pool over VPT=4 consecutive vertices,
//           2 = lane-shfl pool over groups of 4 lanes (VPT=1)
template <int V, int FIN, int NPH, int FOUT, int VPT, int POOLMODE>
__global__ __launch_bounds__(256) void k_conv(
    const float* __restrict__ xin, const float* __restrict__ W,
    const float* __restrict__ bias, float* __restrict__ out,
    const int* __restrict__ off, const int* __restrict__ scol,
    const float* __restrict__ sval) {
    constexpr int FH = FIN / NPH;                 // features per phase
    constexpr int SR = (FH == 3) ? 5 : FH + 2;    // padded LDS row stride (bank spread)
    constexpr int IBL = (VPT == 4) ? 2 : 1;       // i-blocking for W-read amortization
    __shared__ float xs0[V * SR];
    __shared__ float xs1[V * SR];
    __shared__ float Wl[3 * FH * FOUT];

    const int t = threadIdx.x;
    const int b = blockIdx.x;

    float acc[VPT][FOUT];
#pragma unroll
    for (int i = 0; i < VPT; ++i)
#pragma unroll
        for (int o = 0; o < FOUT; ++o) acc[i][o] = 0.f;

    for (int ph = 0; ph < NPH; ++ph) {
        // ---- load transformed weight panels for this feature slice
        for (int idx = t; idx < FH * FOUT; idx += 256) {
            int f = idx / FOUT, o = idx - f * FOUT;
            int fg = ph * FH + f;
            float w0 = W[o * (3 * FIN) + fg * 3 + 0];
            float w1 = W[o * (3 * FIN) + fg * 3 + 1];
            float w2 = W[o * (3 * FIN) + fg * 3 + 2];
            Wl[f * FOUT + o] = w0 - w2;
            Wl[(FH + f) * FOUT + o] = w1;
            Wl[(2 * FH + f) * FOUT + o] = 2.f * w2;
        }
        // ---- stage x0 feature-slice into LDS
        if constexpr (FH == 3) {
            for (int r = t; r < V * 3; r += 256) {
                int v = r / 3, f = r - v * 3;
                xs0[v * SR + f] = xin[(size_t)b * (V * 3) + r];
            }
        } else {
            for (int r = t; r < V * (FH / 4); r += 256) {
                int v = r / (FH / 4), j = r - v * (FH / 4);
                float4 q = *(const float4*)(xin + (size_t)(b * V + v) * FIN + ph * FH + j * 4);
                xs0[v * SR + j * 4 + 0] = q.x;
                xs0[v * SR + j * 4 + 1] = q.y;
                xs0[v * SR + j * 4 + 2] = q.z;
                xs0[v * SR + j * 4 + 3] = q.w;
            }
        }
        __syncthreads();

        // ---- x1 = L x0 (LDS gather, write to xs1)
#pragma unroll
        for (int i = 0; i < VPT; ++i) {
            int v = t * VPT + i;
            float x1r[FH];
#pragma unroll
            for (int f = 0; f < FH; ++f) x1r[f] = 0.f;
            int s = off[v], e = off[v + 1];
            for (int p = s; p < e; ++p) {
                int c = scol[p] * SR;
                float w = sval[p];
#pragma unroll
                for (int f = 0; f < FH; ++f) x1r[f] += w * xs0[c + f];
            }
#pragma unroll
            for (int f = 0; f < FH; ++f) xs1[v * SR + f] = x1r[f];
        }
        __syncthreads();

        // ---- g = L x1, then GEMM accumulate
#pragma unroll
        for (int i0 = 0; i0 < VPT; i0 += IBL) {
            float u[IBL][3 * FH];
#pragma unroll
            for (int ii = 0; ii < IBL; ++ii) {
                int v = t * VPT + i0 + ii;
#pragma unroll
                for (int f = 0; f < FH; ++f) u[ii][2 * FH + f] = 0.f;
                int s = off[v], e = off[v + 1];
                for (int p = s; p < e; ++p) {
                    int c = scol[p] * SR;
                    float w = sval[p];
#pragma unroll
                    for (int f = 0; f < FH; ++f) u[ii][2 * FH + f] += w * xs1[c + f];
                }
#pragma unroll
                for (int f = 0; f < FH; ++f) {
                    u[ii][f] = xs0[v * SR + f];
                    u[ii][FH + f] = xs1[v * SR + f];
                }
            }
#pragma unroll
            for (int j = 0; j < 3 * FH; ++j) {
#pragma unroll
                for (int o4 = 0; o4 < FOUT / 4; ++o4) {
                    float4 wv = *(const float4*)&Wl[j * FOUT + o4 * 4];
#pragma unroll
                    for (int ii = 0; ii < IBL; ++ii) {
                        acc[i0 + ii][o4 * 4 + 0] += u[ii][j] * wv.x;
                        acc[i0 + ii][o4 * 4 + 1] += u[ii][j] * wv.y;
                        acc[i0 + ii][o4 * 4 + 2] += u[ii][j] * wv.z;
                        acc[i0 + ii][o4 * 4 + 3] += u[ii][j] * wv.w;
                    }
                }
            }
        }
        __syncthreads();  // protect LDS before next phase overwrites
    }

    // ---- epilogue: bias (+ optional pool) + store
    if constexpr (POOLMODE == 0) {
#pragma unroll
        for (int i = 0; i < VPT; ++i) {
            int v = t * VPT + i;
            float* orow = out + ((size_t)b * V + v) * FOUT;
#pragma unroll
            for (int o4 = 0; o4 < FOUT / 4; ++o4) {
                float4 st;
                st.x = acc[i][o4 * 4 + 0] + bias[o4 * 4 + 0];
                st.y = acc[i][o4 * 4 + 1] + bias[o4 * 4 + 1];
                st.z = acc[i][o4 * 4 + 2] + bias[o4 * 4 + 2];
                st.w = acc[i][o4 * 4 + 3] + bias[o4 * 4 + 3];
                ((float4*)orow)[o4] = st;
            }
        }
    } else if constexpr (POOLMODE == 1) {
        float* orow = out + ((size_t)b * (V / 4) + t) * FOUT;
#pragma unroll
        for (int o4 = 0; o4 < FOUT / 4; ++o4) {
            float4 st;
#pragma unroll
            for (int q = 0; q < 4; ++q) {
                int o = o4 * 4 + q;
                float m = fmaxf(fmaxf(acc[0][o], acc[1][o]), fmaxf(acc[2][o], acc[3][o]));
                ((float*)&st)[q] = m + bias[o];
            }
            ((float4*)orow)[o4] = st;
        }
    } else {
        // lane-shfl pool over 4 consecutive lanes (v = t, VPT = 1)
#pragma unroll
        for (int o = 0; o < FOUT; ++o) {
            float m = acc[0][o];
            m = fmaxf(m, __shfl_xor(m, 1));
            m = fmaxf(m, __shfl_xor(m, 2));
            acc[0][o] = m + bias[o];
        }
        if ((t & 3) == 0) {
            float* orow = out + ((size_t)b * (V / 4) + (t >> 2)) * FOUT;
#pragma unroll
            for (int o4 = 0; o4 < FOUT / 4; ++o4) {
                float4 st = {acc[0][o4 * 4 + 0], acc[0][o4 * 4 + 1],
                             acc[0][o4 * 4 + 2], acc[0][o4 * 4 + 3]};
                ((float4*)orow)[o4] = st;
            }
        }
    }
}

// ---------------- FC1: C[512,512] = A[512,4096] * W[512,4096]^T, split-K=16 ----------------
__global__ __launch_bounds__(256) void k_fc1(const float* __restrict__ A,
                                             const float* __restrict__ W,
                                             float* __restrict__ part) {
    __shared__ float As[16][128];
    __shared__ float Bs[16][128];
    const int tid = threadIdx.x;
    const int bm = blockIdx.x, bn = blockIdx.y, bz = blockIdx.z;
    const int m0 = (tid >> 4) << 3;
    const int n0 = (tid & 15) << 3;
    float acc[8][8];
#pragma unroll
    for (int i = 0; i < 8; ++i)
#pragma unroll
        for (int j = 0; j < 8; ++j) acc[i][j] = 0.f;
    const int r = tid >> 1;
    const int c8 = (tid & 1) << 3;
    const float* Ar = A + (size_t)(bm * 128 + r) * 4096 + bz * 256 + c8;
    const float* Wr = W + (size_t)(bn * 128 + r) * 4096 + bz * 256 + c8;
    for (int kt = 0; kt < 256; kt += 16) {
        float4 a0 = *(const float4*)(Ar + kt);
        float4 a1 = *(const float4*)(Ar + kt + 4);
        float4 w0 = *(const float4*)(Wr + kt);
        float4 w1 = *(const float4*)(Wr + kt + 4);
        __syncthreads();
        As[c8 + 0][r] = a0.x; As[c8 + 1][r] = a0.y; As[c8 + 2][r] = a0.z; As[c8 + 3][r] = a0.w;
        As[c8 + 4][r] = a1.x; As[c8 + 5][r] = a1.y; As[c8 + 6][r] = a1.z; As[c8 + 7][r] = a1.w;
        Bs[c8 + 0][r] = w0.x; Bs[c8 + 1][r] = w0.y; Bs[c8 + 2][r] = w0.z; Bs[c8 + 3][r] = w0.w;
        Bs[c8 + 4][r] = w1.x; Bs[c8 + 5][r] = w1.y; Bs[c8 + 6][r] = w1.z; Bs[c8 + 7][r] = w1.w;
        __syncthreads();
#pragma unroll
        for (int k = 0; k < 16; ++k) {
            float am[8], bn_[8];
            *(float4*)&am[0] = *(const float4*)&As[k][m0];
            *(float4*)&am[4] = *(const float4*)&As[k][m0 + 4];
            *(float4*)&bn_[0] = *(const float4*)&Bs[k][n0];
            *(float4*)&bn_[4] = *(const float4*)&Bs[k][n0 + 4];
#pragma unroll
            for (int i = 0; i < 8; ++i)
#pragma unroll
                for (int j = 0; j < 8; ++j) acc[i][j] += am[i] * bn_[j];
        }
    }
    float* P = part + ((size_t)bz * 512 + bm * 128 + m0) * 512 + bn * 128 + n0;
#pragma unroll
    for (int i = 0; i < 8; ++i) {
        float4 s0 = {acc[i][0], acc[i][1], acc[i][2], acc[i][3]};
        float4 s1 = {acc[i][4], acc[i][5], acc[i][6], acc[i][7]};
        *(float4*)(P + i * 512) = s0;
        *(float4*)(P + i * 512 + 4) = s1;
    }
}

__global__ void k_fc1red(const float* __restrict__ part, const float* __restrict__ bias,
                         float* __restrict__ out) {
    int t = blockIdx.x * 256 + threadIdx.x;  // 512*512
    float s = bias[t & 511];
#pragma unroll
    for (int z = 0; z < 16; ++z) s += part[(size_t)z * 262144 + t];
    out[t] = s;
}

// ---------------- FC2: out[512,63] ----------------
__global__ void k_fc2(const float* __restrict__ X, const float* __restrict__ W,
                      const float* __restrict__ bias, float* __restrict__ out) {
    int b = blockIdx.x, c = threadIdx.x;
    if (c >= 63) return;
    const float4* xr = (const float4*)(X + b * 512);
    const float4* wr = (const float4*)(W + c * 512);
    float s = 0.f;
    for (int k = 0; k < 128; ++k) {
        float4 xv = xr[k], wv = wr[k];
        s += xv.x * wv.x + xv.y * wv.y + xv.z * wv.z + xv.w * wv.w;
    }
    out[b * 63 + c] = s + bias[c];
}

extern "C" void kernel_launch(void* const* d_in, const int* in_sizes, int n_in,
                              void* d_out, int out_size, void* d_ws, size_t ws_size,
                              hipStream_t stream) {
    const float* x = (const float*)d_in[0];
    const int* rows0 = (const int*)d_in[1];
    const int* cols0 = (const int*)d_in[2];
    const float* vals0 = (const float*)d_in[3];
    const int* rows1 = (const int*)d_in[4];
    const int* cols1 = (const int*)d_in[5];
    const float* vals1 = (const float*)d_in[6];
    const float* W0 = (const float*)d_in[7];  const float* b0 = (const float*)d_in[8];
    const float* W1 = (const float*)d_in[9];  const float* b1 = (const float*)d_in[10];
    const float* W2 = (const float*)d_in[11]; const float* b2 = (const float*)d_in[12];
    const float* W3 = (const float*)d_in[13]; const float* b3 = (const float*)d_in[14];
    const float* fcW1 = (const float*)d_in[15]; const float* fcb1 = (const float*)d_in[16];
    const float* fcW2 = (const float*)d_in[17]; const float* fcb2 = (const float*)d_in[18];
    float* out = (float*)d_out;

    float* wsf = (float*)d_ws;
    // CSR region (aliased ints/floats), 65536 floats
    int* off0 = (int*)(wsf + 0);          // 1025
    int* scol0 = (int*)(wsf + 2048);      // 8192
    float* sval0 = wsf + 10240;           // 8192
    int* off1 = (int*)(wsf + 18432);      // 257
    int* scol1 = (int*)(wsf + 20480);     // 2048
    float* sval1 = wsf + 22528;           // 2048
    int* deg0 = (int*)(wsf + 24576);      // 1024
    int* deg1 = (int*)(wsf + 25600);      // 256

    float* A1  = wsf + 65536;             // 16,777,216  [B,1024,32]
    float* P1  = A1 + 16777216;           //  4,194,304  [B,256,32]
    float* A3  = P1 + 4194304;            //  8,388,608  [B,256,64]
    float* FCB = A3 + 8388608;            //  2,097,152  [B,4096]
    float* PART = FCB + 2097152;          //  4,194,304  [16,512,512]
    float* FC1O = PART + 4194304;         //    262,144  [512,512]
    (void)in_sizes; (void)n_in; (void)out_size; (void)ws_size;

    hipMemsetAsync(wsf, 0, 65536 * 4, stream);
    k_deg<<<E0 / 256, 256, 0, stream>>>(rows0, E0, deg0);
    k_deg<<<E1 / 256, 256, 0, stream>>>(rows1, E1, deg1);
    k_scan<<<1, 1024, 0, stream>>>(deg0, off0, V0);
    k_scan<<<1, 1024, 0, stream>>>(deg1, off1, V1);
    k_fill<<<E0 / 256, 256, 0, stream>>>(rows0, cols0, vals0, E0, off0, scol0, sval0);
    k_fill<<<E1 / 256, 256, 0, stream>>>(rows1, cols1, vals1, E1, off1, scol1, sval1);

    // conv1: level0, 3->32, no pool.           LDS ~41 KB
    k_conv<V0, 3, 1, 32, 4, 0><<<BB, 256, 0, stream>>>(x, W0, b0, A1, off0, scol0, sval0);
    // conv2+pool: level0, 32->32, 2 phases.    LDS ~150 KB
    k_conv<V0, 32, 2, 32, 4, 1><<<BB, 256, 0, stream>>>(A1, W1, b1, P1, off0, scol0, sval0);
    // conv3: level1, 32->64, 2 phases.         LDS ~48 KB
    k_conv<V1, 32, 2, 64, 1, 0><<<BB, 256, 0, stream>>>(P1, W2, b2, A3, off1, scol1, sval1);
    // conv4+pool: level1, 64->64, 4 phases.    LDS ~48 KB
    k_conv<V1, 64, 4, 64, 1, 2><<<BB, 256, 0, stream>>>(A3, W3, b3, FCB, off1, scol1, sval1);

    // head (FCB is already [B, 4096] in reference order)
    k_fc1<<<dim3(4, 4, 16), 256, 0, stream>>>(FCB, fcW1, PART);
    k_fc1red<<<1024, 256, 0, stream>>>(PART, fcb1, FC1O);
    k_fc2<<<BB, 64, 0, stream>>>(FC1O, fcW2, fcb2, out);
}

// Round 3
// 615.311 us; speedup vs baseline: 2.7473x; 2.7473x over previous
//
#include <hip/hip_runtime.h>

#define BB 512
#define V0 1024
#define V1 256
#define E0 8192
#define E1 2048

// ---------------- CSR build (deterministic) ----------------
__global__ void k_deg(const int* __restrict__ rows, int E, int* __restrict__ deg) {
    int t = blockIdx.x * 256 + threadIdx.x;
    if (t < E) atomicAdd(&deg[rows[t]], 1);
}

__global__ void k_scan(const int* __restrict__ deg, int* __restrict__ off, int V) {
    __shared__ int s[1024];
    int t = threadIdx.x;
    s[t] = (t < V) ? deg[t] : 0;
    __syncthreads();
    for (int d = 1; d < 1024; d <<= 1) {
        int val = (t >= d) ? s[t - d] : 0;
        __syncthreads();
        s[t] += val;
        __syncthreads();
    }
    if (t < V) off[t + 1] = s[t];
    if (t == 0) off[0] = 0;
}

// stable fill: edge e goes to off[row] + (#earlier edges with same row)
__global__ void k_fill(const int* __restrict__ rows, const int* __restrict__ cols,
                       const float* __restrict__ vals, int E,
                       const int* __restrict__ off, int* __restrict__ scol,
                       float* __restrict__ sval) {
    __shared__ int rs[256];
    int e = blockIdx.x * 256 + threadIdx.x;
    int r = (e < E) ? rows[e] : -1;
    int rank = 0;
    for (int c0 = 0; c0 <= (int)blockIdx.x; ++c0) {
        __syncthreads();
        int idx = c0 * 256 + threadIdx.x;
        rs[threadIdx.x] = (idx < E) ? rows[idx] : -2;
        __syncthreads();
        int lim = e - c0 * 256;
        if (lim > 256) lim = 256;
        for (int j = 0; j < lim; ++j) rank += (rs[j] == r) ? 1 : 0;
    }
    if (e < E) {
        int p = off[r] + rank;
        scol[p] = cols[e];
        sval[p] = vals[e];
    }
}

// ---------------- fused cheby conv, batch-major, feature-major LDS ----------------
// xin [B, V, FIN] (row-major), out [B, V or V/4, FOUT].
// Block = 1024 threads covering NB batch-slices of V vertices (NB*V == 1024).
// Per phase (FH input features): stage x0 slice (feature-major [f][col]),
// x1 = L x0 -> LDS, x2raw = L x1 -> LDS, then register-tiled GEMM
// acc += [x0|x1|x2raw]^T (K=3*FH) * Wl (transformed panels: W0-W2 | W1 | 2*W2).
// POOL: 0 = none, 1 = max over the thread's 4-vertex microtile (stride-4 pool).
template <int V, int NB, int FIN, int FH, int FOUT, int POOL>
__global__ __launch_bounds__(1024) void k_conv(
    const float* __restrict__ xin, const float* __restrict__ W,
    const float* __restrict__ bias, float* __restrict__ out,
    const int* __restrict__ off, const int* __restrict__ scol,
    const float* __restrict__ sval) {
    constexpr int NPH = FIN / FH;
    constexpr int OW = FOUT / 4;   // outputs per thread
    constexpr int NC = NB * V;     // 1024 LDS columns
    static_assert(NC == 1024, "block must cover 1024 (b,v) pairs");
    __shared__ float xsA[3 * FH * NC];
    __shared__ float Wl[3 * FH * FOUT];

    const int t = threadIdx.x;
    const int bb = t / V;
    const int vloc = t - bb * V;
    const int b = blockIdx.x * NB + bb;
    const int vt = vloc >> 2;
    const int ot = vloc & 3;
    const int o0 = ot * OW;
    const int colg = bb * V;

    const int s0 = off[vloc];
    const int e0 = off[vloc + 1];

    float acc[4][OW];
#pragma unroll
    for (int i = 0; i < 4; ++i)
#pragma unroll
        for (int o = 0; o < OW; ++o) acc[i][o] = 0.f;

    for (int ph = 0; ph < NPH; ++ph) {
        // ---- transformed weight panels for this feature slice (k-major [k][o])
        for (int idx = t; idx < FH * FOUT; idx += 1024) {
            int f = idx / FOUT, o = idx - f * FOUT;
            int fg = ph * FH + f;
            float w0 = W[o * (3 * FIN) + fg * 3 + 0];
            float w1 = W[o * (3 * FIN) + fg * 3 + 1];
            float w2 = W[o * (3 * FIN) + fg * 3 + 2];
            Wl[f * FOUT + o] = w0 - w2;
            Wl[(FH + f) * FOUT + o] = w1;
            Wl[(2 * FH + f) * FOUT + o] = 2.f * w2;
        }
        // ---- stage x0 feature slice, feature-major
        if constexpr (FH == 3) {
#pragma unroll
            for (int f = 0; f < 3; ++f)
                xsA[f * NC + colg + vloc] = xin[((size_t)b * V + vloc) * 3 + f];
        } else {
#pragma unroll
            for (int j = 0; j < FH / 4; ++j) {
                float4 q = *(const float4*)(xin + ((size_t)b * V + vloc) * FIN + ph * FH + 4 * j);
                xsA[(4 * j + 0) * NC + colg + vloc] = q.x;
                xsA[(4 * j + 1) * NC + colg + vloc] = q.y;
                xsA[(4 * j + 2) * NC + colg + vloc] = q.z;
                xsA[(4 * j + 3) * NC + colg + vloc] = q.w;
            }
        }
        __syncthreads();
        // ---- x1 = L x0
        {
            float r[FH];
#pragma unroll
            for (int f = 0; f < FH; ++f) r[f] = 0.f;
            for (int p = s0; p < e0; ++p) {
                int c = colg + scol[p];
                float w = sval[p];
#pragma unroll
                for (int f = 0; f < FH; ++f) r[f] += w * xsA[f * NC + c];
            }
#pragma unroll
            for (int f = 0; f < FH; ++f) xsA[(FH + f) * NC + colg + vloc] = r[f];
        }
        __syncthreads();
        // ---- x2raw = L x1
        {
            float r[FH];
#pragma unroll
            for (int f = 0; f < FH; ++f) r[f] = 0.f;
            for (int p = s0; p < e0; ++p) {
                int c = colg + scol[p];
                float w = sval[p];
#pragma unroll
                for (int f = 0; f < FH; ++f) r[f] += w * xsA[(FH + f) * NC + c];
            }
#pragma unroll
            for (int f = 0; f < FH; ++f) xsA[(2 * FH + f) * NC + colg + vloc] = r[f];
        }
        __syncthreads();
        // ---- GEMM accumulate: K = 3*FH
        {
            const int a0 = colg + 4 * vt;
#pragma unroll 4
            for (int k = 0; k < 3 * FH; ++k) {
                float4 a = *(const float4*)&xsA[k * NC + a0];
                float av[4] = {a.x, a.y, a.z, a.w};
#pragma unroll
                for (int j = 0; j < OW / 4; ++j) {
                    float4 wv = *(const float4*)&Wl[k * FOUT + o0 + 4 * j];
#pragma unroll
                    for (int i = 0; i < 4; ++i) {
                        acc[i][4 * j + 0] += av[i] * wv.x;
                        acc[i][4 * j + 1] += av[i] * wv.y;
                        acc[i][4 * j + 2] += av[i] * wv.z;
                        acc[i][4 * j + 3] += av[i] * wv.w;
                    }
                }
            }
        }
        __syncthreads();  // protect LDS before next phase overwrites
    }

    // ---- epilogue
    if constexpr (POOL == 0) {
#pragma unroll
        for (int i = 0; i < 4; ++i) {
            float* orow = out + ((size_t)b * V + 4 * vt + i) * FOUT + o0;
#pragma unroll
            for (int j = 0; j < OW / 4; ++j) {
                float4 st;
                st.x = acc[i][4 * j + 0] + bias[o0 + 4 * j + 0];
                st.y = acc[i][4 * j + 1] + bias[o0 + 4 * j + 1];
                st.z = acc[i][4 * j + 2] + bias[o0 + 4 * j + 2];
                st.w = acc[i][4 * j + 3] + bias[o0 + 4 * j + 3];
                ((float4*)orow)[j] = st;
            }
        }
    } else {
        float* orow = out + ((size_t)b * (V / 4) + vt) * FOUT + o0;
#pragma unroll
        for (int j = 0; j < OW / 4; ++j) {
            float4 st;
#pragma unroll
            for (int q = 0; q < 4; ++q) {
                int o = 4 * j + q;
                float m = fmaxf(fmaxf(acc[0][o], acc[1][o]), fmaxf(acc[2][o], acc[3][o]));
                ((float*)&st)[q] = m + bias[o0 + o];
            }
            ((float4*)orow)[j] = st;
        }
    }
}

// ---------------- FC1: C[512,512] = A[512,4096] * W[512,4096]^T, split-K=16 ----------------
__global__ __launch_bounds__(256) void k_fc1(const float* __restrict__ A,
                                             const float* __restrict__ W,
                                             float* __restrict__ part) {
    __shared__ float As[16][128];
    __shared__ float Bs[16][128];
    const int tid = threadIdx.x;
    const int bm = blockIdx.x, bn = blockIdx.y, bz = blockIdx.z;
    const int m0 = (tid >> 4) << 3;
    const int n0 = (tid & 15) << 3;
    float acc[8][8];
#pragma unroll
    for (int i = 0; i < 8; ++i)
#pragma unroll
        for (int j = 0; j < 8; ++j) acc[i][j] = 0.f;
    const int r = tid >> 1;
    const int c8 = (tid & 1) << 3;
    const float* Ar = A + (size_t)(bm * 128 + r) * 4096 + bz * 256 + c8;
    const float* Wr = W + (size_t)(bn * 128 + r) * 4096 + bz * 256 + c8;
    for (int kt = 0; kt < 256; kt += 16) {
        float4 a0 = *(const float4*)(Ar + kt);
        float4 a1 = *(const float4*)(Ar + kt + 4);
        float4 w0 = *(const float4*)(Wr + kt);
        float4 w1 = *(const float4*)(Wr + kt + 4);
        __syncthreads();
        As[c8 + 0][r] = a0.x; As[c8 + 1][r] = a0.y; As[c8 + 2][r] = a0.z; As[c8 + 3][r] = a0.w;
        As[c8 + 4][r] = a1.x; As[c8 + 5][r] = a1.y; As[c8 + 6][r] = a1.z; As[c8 + 7][r] = a1.w;
        Bs[c8 + 0][r] = w0.x; Bs[c8 + 1][r] = w0.y; Bs[c8 + 2][r] = w0.z; Bs[c8 + 3][r] = w0.w;
        Bs[c8 + 4][r] = w1.x; Bs[c8 + 5][r] = w1.y; Bs[c8 + 6][r] = w1.z; Bs[c8 + 7][r] = w1.w;
        __syncthreads();
#pragma unroll
        for (int k = 0; k < 16; ++k) {
            float am[8], bn_[8];
            *(float4*)&am[0] = *(const float4*)&As[k][m0];
            *(float4*)&am[4] = *(const float4*)&As[k][m0 + 4];
            *(float4*)&bn_[0] = *(const float4*)&Bs[k][n0];
            *(float4*)&bn_[4] = *(const float4*)&Bs[k][n0 + 4];
#pragma unroll
            for (int i = 0; i < 8; ++i)
#pragma unroll
                for (int j = 0; j < 8; ++j) acc[i][j] += am[i] * bn_[j];
        }
    }
    float* P = part + ((size_t)bz * 512 + bm * 128 + m0) * 512 + bn * 128 + n0;
#pragma unroll
    for (int i = 0; i < 8; ++i) {
        float4 s0 = {acc[i][0], acc[i][1], acc[i][2], acc[i][3]};
        float4 s1 = {acc[i][4], acc[i][5], acc[i][6], acc[i][7]};
        *(float4*)(P + i * 512) = s0;
        *(float4*)(P + i * 512 + 4) = s1;
    }
}

__global__ void k_fc1red(const float* __restrict__ part, const float* __restrict__ bias,
                         float* __restrict__ out) {
    int t = blockIdx.x * 256 + threadIdx.x;  // 512*512
    float s = bias[t & 511];
#pragma unroll
    for (int z = 0; z < 16; ++z) s += part[(size_t)z * 262144 + t];
    out[t] = s;
}

// ---------------- FC2: out[512,63] ----------------
__global__ void k_fc2(const float* __restrict__ X, const float* __restrict__ W,
                      const float* __restrict__ bias, float* __restrict__ out) {
    int b = blockIdx.x, c = threadIdx.x;
    if (c >= 63) return;
    const float4* xr = (const float4*)(X + b * 512);
    const float4* wr = (const float4*)(W + c * 512);
    float s = 0.f;
    for (int k = 0; k < 128; ++k) {
        float4 xv = xr[k], wv = wr[k];
        s += xv.x * wv.x + xv.y * wv.y + xv.z * wv.z + xv.w * wv.w;
    }
    out[b * 63 + c] = s + bias[c];
}

extern "C" void kernel_launch(void* const* d_in, const int* in_sizes, int n_in,
                              void* d_out, int out_size, void* d_ws, size_t ws_size,
                              hipStream_t stream) {
    const float* x = (const float*)d_in[0];
    const int* rows0 = (const int*)d_in[1];
    const int* cols0 = (const int*)d_in[2];
    const float* vals0 = (const float*)d_in[3];
    const int* rows1 = (const int*)d_in[4];
    const int* cols1 = (const int*)d_in[5];
    const float* vals1 = (const float*)d_in[6];
    const float* W0 = (const float*)d_in[7];  const float* b0 = (const float*)d_in[8];
    const float* W1 = (const float*)d_in[9];  const float* b1 = (const float*)d_in[10];
    const float* W2 = (const float*)d_in[11]; const float* b2 = (const float*)d_in[12];
    const float* W3 = (const float*)d_in[13]; const float* b3 = (const float*)d_in[14];
    const float* fcW1 = (const float*)d_in[15]; const float* fcb1 = (const float*)d_in[16];
    const float* fcW2 = (const float*)d_in[17]; const float* fcb2 = (const float*)d_in[18];
    float* out = (float*)d_out;

    float* wsf = (float*)d_ws;
    // CSR region (aliased ints/floats), 65536 floats
    int* off0 = (int*)(wsf + 0);          // 1025
    int* scol0 = (int*)(wsf + 2048);      // 8192
    float* sval0 = wsf + 10240;           // 8192
    int* off1 = (int*)(wsf + 18432);      // 257
    int* scol1 = (int*)(wsf + 20480);     // 2048
    float* sval1 = wsf + 22528;           // 2048
    int* deg0 = (int*)(wsf + 24576);      // 1024
    int* deg1 = (int*)(wsf + 25600);      // 256

    float* A1  = wsf + 65536;             // 16,777,216  [B,1024,32]
    float* P1  = A1 + 16777216;           //  4,194,304  [B,256,32]
    float* A3  = P1 + 4194304;            //  8,388,608  [B,256,64]
    float* FCB = A3 + 8388608;            //  2,097,152  [B,4096]
    float* PART = FCB + 2097152;          //  4,194,304  [16,512,512]
    float* FC1O = PART + 4194304;         //    262,144  [512,512]
    (void)in_sizes; (void)n_in; (void)out_size; (void)ws_size;

    hipMemsetAsync(wsf, 0, 65536 * 4, stream);
    k_deg<<<E0 / 256, 256, 0, stream>>>(rows0, E0, deg0);
    k_deg<<<E1 / 256, 256, 0, stream>>>(rows1, E1, deg1);
    k_scan<<<1, 1024, 0, stream>>>(deg0, off0, V0);
    k_scan<<<1, 1024, 0, stream>>>(deg1, off1, V1);
    k_fill<<<E0 / 256, 256, 0, stream>>>(rows0, cols0, vals0, E0, off0, scol0, sval0);
    k_fill<<<E1 / 256, 256, 0, stream>>>(rows1, cols1, vals1, E1, off1, scol1, sval1);

    // conv1: level0, 3->32            LDS 38 KB,  acc 32
    k_conv<V0, 1, 3, 3, 32, 0><<<BB, 1024, 0, stream>>>(x, W0, b0, A1, off0, scol0, sval0);
    // conv2+pool: level0, 32->32      LDS 101 KB, acc 32
    k_conv<V0, 1, 32, 8, 32, 1><<<BB, 1024, 0, stream>>>(A1, W1, b1, P1, off0, scol0, sval0);
    // conv3: level1, 32->64, 4 b/blk  LDS 104 KB, acc 64
    k_conv<V1, 4, 32, 8, 64, 0><<<BB / 4, 1024, 0, stream>>>(P1, W2, b2, A3, off1, scol1, sval1);
    // conv4+pool: level1, 64->64      LDS 104 KB, acc 64
    k_conv<V1, 4, 64, 8, 64, 1><<<BB / 4, 1024, 0, stream>>>(A3, W3, b3, FCB, off1, scol1, sval1);

    // head (FCB is [B, 4096] in reference order)
    k_fc1<<<dim3(4, 4, 16), 256, 0, stream>>>(FCB, fcW1, PART);
    k_fc1red<<<1024, 256, 0, stream>>>(PART, fcb1, FC1O);
    k_fc2<<<BB, 64, 0, stream>>>(FC1O, fcW2, fcb2, out);
}